// Round 3
// baseline (180.040 us; speedup 1.0000x reference)
//
#include <hip/hip_runtime.h>
#include <math.h>

// out [1, 128, N] f32:
//   rows   0.. 63 : pdf^T               (pdf [N,64] row-major)  -> transpose_kernel
//   rows  64.. 95 : te[c] broadcast                             -> bcast_kernel
//   rows  96..127 : mask[p] ? me1[c] : me0[c]                   -> bcast_kernel
//
// ws layout: te[0..31], me0[32..63], me1[64..95]

#define HALF 32

__global__ void embed_small_kernel(const float* __restrict__ t,
                                   const float* __restrict__ ef_w1, const float* __restrict__ ef_b1,
                                   const float* __restrict__ ef_w2, const float* __restrict__ ef_b2,
                                   const float* __restrict__ em_w1, const float* __restrict__ em_b1,
                                   const float* __restrict__ em_w2, const float* __restrict__ em_b2,
                                   float* __restrict__ ws) {
    __shared__ float h[3][64];
    const int tid = threadIdx.x;
    const float log_scale = 0.2970934777f;  // ln(10000)/31

    if (tid < 192) {
        const int v = tid >> 6;      // 0: sin-emb(t)->ef, 1: sin-emb(0)->em, 2: sin-emb(1)->em
        const int j = tid & 63;
        const float val = (v == 0) ? t[0] : (float)(v - 1);
        const float* w1 = (v == 0) ? ef_w1 : em_w1;
        const float* b1 = (v == 0) ? ef_b1 : em_b1;
        float acc = b1[j];
        for (int k = 0; k < HALF; ++k) {
            float f = expf(-(float)k * log_scale);
            float ang = val * f;
            float s, c;
            sincosf(ang, &s, &c);
            acc += s * w1[j * 64 + k] + c * w1[j * 64 + HALF + k];
        }
        h[v][j] = (acc > 0.0f) ? acc : 0.1f * acc;  // LeakyReLU(0.1)
    }
    __syncthreads();
    if (tid < 96) {
        const int v = tid >> 5;
        const int c = tid & 31;
        const float* w2 = (v == 0) ? ef_w2 : em_w2;
        const float* b2 = (v == 0) ? ef_b2 : em_b2;
        float acc = b2[c];
        for (int j = 0; j < 64; ++j) acc += h[v][j] * w2[c * 64 + j];
        ws[v * 32 + c] = acc;
    }
}

// ---------------------------------------------------------------------------
// Broadcast kernel: rows 64..127. Block = 4096 points, 256 threads.
// Outer loop over rows => each row's 16 KB span written as one contiguous
// burst (single active write stream per block). Pure-write, fill-like.
// ---------------------------------------------------------------------------
#define BSP 4096

__global__ __launch_bounds__(256) void bcast_kernel(
        const int* __restrict__ mask,
        const float* __restrict__ ws,
        float* __restrict__ out,
        int N) {
    const int tid = threadIdx.x;
    const long long p0 = (long long)blockIdx.x * BSP;

    if (p0 + BSP <= (long long)N) {
        // preload this thread's mask columns: cols p0 + 4*tid + 1024*i
        int4 m[4];
        #pragma unroll
        for (int i = 0; i < 4; ++i)
            m[i] = ((const int4*)mask)[(p0 >> 2) + tid + 256 * i];

        for (int r = 64; r < 96; ++r) {
            const float e = ws[r - 64];          // uniform scalar load (L2)
            const float4 v = make_float4(e, e, e, e);
            float* op = out + (long long)r * N + p0 + 4 * tid;
            #pragma unroll
            for (int i = 0; i < 4; ++i)
                *(float4*)(op + 1024 * i) = v;
        }
        for (int r = 96; r < 128; ++r) {
            const float e0 = ws[32 + (r - 96)];
            const float e1 = ws[64 + (r - 96)];
            float* op = out + (long long)r * N + p0 + 4 * tid;
            #pragma unroll
            for (int i = 0; i < 4; ++i) {
                const float4 v = make_float4(m[i].x ? e1 : e0, m[i].y ? e1 : e0,
                                             m[i].z ? e1 : e0, m[i].w ? e1 : e0);
                *(float4*)(op + 1024 * i) = v;
            }
        }
    } else {
        // tail block: per-element guards
        for (int r = 64; r < 128; ++r) {
            const bool is_mask = (r >= 96);
            const float e  = is_mask ? 0.f : ws[r - 64];
            const float e0 = is_mask ? ws[32 + (r - 96)] : 0.f;
            const float e1 = is_mask ? ws[64 + (r - 96)] : 0.f;
            for (int i = 0; i < 4; ++i) {
                const long long base = p0 + 4 * tid + 1024 * i;
                #pragma unroll
                for (int j = 0; j < 4; ++j) {
                    const long long col = base + j;
                    if (col < (long long)N) {
                        float v = e;
                        if (is_mask) v = mask[col] ? e1 : e0;
                        out[(long long)r * N + col] = v;
                    }
                }
            }
        }
    }
}

// ---------------------------------------------------------------------------
// Transpose kernel: rows 0..63. Block = 512 points, 512 threads,
// LDS 64x512 f32 = 128 KiB, XOR swizzle p ^= 4*((c>>2)&7):
//   phase-1 scalar writes: banks 4*(w^m)+e -> 32 banks x 2 lanes (free)
//   phase-2 ds_read_b128:  stride-1 pattern -> conflict-free
// ---------------------------------------------------------------------------
#define TSP 512

__global__ __launch_bounds__(512) void transpose_kernel(
        const float* __restrict__ pdf,
        float* __restrict__ out,
        int N) {
    __shared__ float tile[64 * TSP];   // exactly 128 KiB

    const int tid = threadIdx.x;
    const long long p0 = (long long)blockIdx.x * TSP;
    const bool fast = (p0 + TSP <= (long long)N);

    // ---- phase 1: pdf [512 pts x 64 ch] -> LDS (channel-major, swizzled) ----
    if (fast) {
        const float4* src = (const float4*)(pdf + p0 * 64);
        #pragma unroll
        for (int it = 0; it < 16; ++it) {
            const int f = tid + it * 512;        // 0..8191
            const int p = f >> 4;                // point in tile
            const int k = f & 15;                // c0 = 4k
            const float4 v = src[f];
            const int base = (k << 2) * TSP + (p ^ ((k & 7) << 2));
            tile[base + 0 * TSP] = v.x;
            tile[base + 1 * TSP] = v.y;
            tile[base + 2 * TSP] = v.z;
            tile[base + 3 * TSP] = v.w;
        }
    } else {
        #pragma unroll
        for (int it = 0; it < 16; ++it) {
            const int f = tid + it * 512;
            const int p = f >> 4;
            const int k = f & 15;
            float4 v = make_float4(0.f, 0.f, 0.f, 0.f);
            if (p0 + p < (long long)N)
                v = ((const float4*)(pdf + (p0 + p) * 64))[k];
            const int base = (k << 2) * TSP + (p ^ ((k & 7) << 2));
            tile[base + 0 * TSP] = v.x;
            tile[base + 1 * TSP] = v.y;
            tile[base + 2 * TSP] = v.z;
            tile[base + 3 * TSP] = v.w;
        }
    }

    __syncthreads();

    // ---- phase 2: wave w writes rows 8w..8w+7, 2 KB contiguous per row ----
    const int l = tid & 63;
    const int w = tid >> 6;

    if (fast) {
        #pragma unroll
        for (int j = 0; j < 8; ++j) {
            const int r = 8 * w + j;
            const int sb = (4 * l) ^ (((r >> 2) & 7) << 2);
            const float4 a = *(const float4*)&tile[r * TSP + sb];
            const float4 b = *(const float4*)&tile[r * TSP + sb + 256];
            float* op = out + (long long)r * N + p0;
            *(float4*)(op + 4 * l)       = a;
            *(float4*)(op + 4 * l + 256) = b;
        }
    } else {
        for (int j = 0; j < 8; ++j) {
            const int r = 8 * w + j;
            const int sb = (4 * l) ^ (((r >> 2) & 7) << 2);
            #pragma unroll
            for (int h = 0; h < 2; ++h) {
                const int pc = 4 * l + 256 * h;
                #pragma unroll
                for (int d = 0; d < 4; ++d) {
                    const long long col = p0 + pc + d;
                    if (col < (long long)N)
                        out[(long long)r * N + col] =
                            tile[r * TSP + ((pc ^ (((r >> 2) & 7) << 2)) + d)];
                }
            }
        }
    }
}

extern "C" void kernel_launch(void* const* d_in, const int* in_sizes, int n_in,
                              void* d_out, int out_size, void* d_ws, size_t ws_size,
                              hipStream_t stream) {
    // 0: inputs [1,6,N]; 1: t [1]; 2: mask [N] i32; 3: pdf [N,64];
    // 4..7: ef_w1,ef_b1,ef_w2,ef_b2; 8..11: em_w1,em_b1,em_w2,em_b2
    const float* t     = (const float*)d_in[1];
    const int*   mask  = (const int*)d_in[2];
    const float* pdf   = (const float*)d_in[3];
    const float* ef_w1 = (const float*)d_in[4];
    const float* ef_b1 = (const float*)d_in[5];
    const float* ef_w2 = (const float*)d_in[6];
    const float* ef_b2 = (const float*)d_in[7];
    const float* em_w1 = (const float*)d_in[8];
    const float* em_b1 = (const float*)d_in[9];
    const float* em_w2 = (const float*)d_in[10];
    const float* em_b2 = (const float*)d_in[11];

    float* out = (float*)d_out;
    float* ws  = (float*)d_ws;
    const int N = in_sizes[2];

    embed_small_kernel<<<1, 192, 0, stream>>>(t, ef_w1, ef_b1, ef_w2, ef_b2,
                                              em_w1, em_b1, em_w2, em_b2, ws);

    const int nb_b = (N + BSP - 1) / BSP;
    bcast_kernel<<<nb_b, 256, 0, stream>>>(mask, ws, out, N);

    const int nb_t = (N + TSP - 1) / TSP;
    transpose_kernel<<<nb_t, 512, 0, stream>>>(pdf, out, N);
}

// Round 4
// 158.233 us; speedup vs baseline: 1.1378x; 1.1378x over previous
//
#include <hip/hip_runtime.h>
#include <math.h>

// out [1, 128, N] f32:
//   rows   0.. 63 : pdf^T               (pdf [N,64] row-major)
//   rows  64.. 95 : te[c] broadcast     (timestep embedding, single vector)
//   rows  96..127 : mask[p] ? me1[c] : me0[c]
//
// ws layout: te[0..31], me0[32..63], me1[64..95]
//
// R3 structure = R0 (best: 64-pt tiles, 256 thr, [64][65] LDS, ~8 blk/CU)
//   + __builtin_nontemporal_load  on pdf/mask (streamed, read-once)
//   + __builtin_nontemporal_store on all output (streamed, write-once)
//   + bijective XCD-contiguous block swizzle (m204)

#define HALF 32

typedef float v4f __attribute__((ext_vector_type(4)));

__global__ void embed_small_kernel(const float* __restrict__ t,
                                   const float* __restrict__ ef_w1, const float* __restrict__ ef_b1,
                                   const float* __restrict__ ef_w2, const float* __restrict__ ef_b2,
                                   const float* __restrict__ em_w1, const float* __restrict__ em_b1,
                                   const float* __restrict__ em_w2, const float* __restrict__ em_b2,
                                   float* __restrict__ ws) {
    __shared__ float h[3][64];
    const int tid = threadIdx.x;
    const float log_scale = 0.2970934777f;  // ln(10000)/31

    if (tid < 192) {
        const int v = tid >> 6;      // 0: sin-emb(t)->ef, 1: sin-emb(0)->em, 2: sin-emb(1)->em
        const int j = tid & 63;
        const float val = (v == 0) ? t[0] : (float)(v - 1);
        const float* w1 = (v == 0) ? ef_w1 : em_w1;
        const float* b1 = (v == 0) ? ef_b1 : em_b1;
        float acc = b1[j];
        for (int k = 0; k < HALF; ++k) {
            float f = expf(-(float)k * log_scale);
            float ang = val * f;
            float s, c;
            sincosf(ang, &s, &c);
            acc += s * w1[j * 64 + k] + c * w1[j * 64 + HALF + k];
        }
        h[v][j] = (acc > 0.0f) ? acc : 0.1f * acc;  // LeakyReLU(0.1)
    }
    __syncthreads();
    if (tid < 96) {
        const int v = tid >> 5;
        const int c = tid & 31;
        const float* w2 = (v == 0) ? ef_w2 : em_w2;
        const float* b2 = (v == 0) ? ef_b2 : em_b2;
        float acc = b2[c];
        for (int j = 0; j < 64; ++j) acc += h[v][j] * w2[c * 64 + j];
        ws[v * 32 + c] = acc;
    }
}

__global__ __launch_bounds__(256) void pvcnn_cond_kernel(
        const float* __restrict__ pdf,
        const int* __restrict__ mask,
        const float* __restrict__ ws,
        float* __restrict__ out,
        int N) {
    __shared__ float tile[64][65];
    __shared__ float emb[96];

    const int tid = threadIdx.x;

    // ---- bijective XCD-contiguous swizzle (m204) ----
    // dispatch round-robins blockIdx across 8 XCDs; remap so each XCD
    // owns one contiguous column slab.
    const int nwg  = gridDim.x;
    const int q    = nwg >> 3;
    const int r    = nwg & 7;
    const int xcd  = blockIdx.x & 7;
    const int j    = blockIdx.x >> 3;
    const int bid  = (xcd < r ? xcd * (q + 1) : r * (q + 1) + (xcd - r) * q) + j;

    const long long p0 = (long long)bid * 64;
    const bool full = (p0 + 64 <= (long long)N);

    if (tid < 96) emb[tid] = ws[tid];

    // ---- phase 1: pdf tile -> LDS (nt loads; read-once stream) ----
    if (full) {
        const v4f* pdf4 = (const v4f*)(pdf + p0 * 64);
        #pragma unroll
        for (int it = 0; it < 4; ++it) {
            int f = tid + it * 256;          // 0..1023
            int p = f >> 4;
            int qq = f & 15;
            v4f v = __builtin_nontemporal_load(pdf4 + p * 16 + qq);
            tile[p][4 * qq + 0] = v.x;
            tile[p][4 * qq + 1] = v.y;
            tile[p][4 * qq + 2] = v.z;
            tile[p][4 * qq + 3] = v.w;
        }
    } else {
        #pragma unroll
        for (int it = 0; it < 4; ++it) {
            int f = tid + it * 256;
            int p = f >> 4;
            int qq = f & 15;
            v4f v = {0.f, 0.f, 0.f, 0.f};
            if (p0 + p < (long long)N) {
                const v4f* pdf4 = (const v4f*)(pdf + (p0 + p) * 64);
                v = __builtin_nontemporal_load(pdf4 + qq);
            }
            tile[p][4 * qq + 0] = v.x;
            tile[p][4 * qq + 1] = v.y;
            tile[p][4 * qq + 2] = v.z;
            tile[p][4 * qq + 3] = v.w;
        }
    }

    const int p  = tid & 63;       // point within tile
    const int wv = tid >> 6;       // wave id 0..3 -> channel sub-offset
    const bool pok = (p0 + p < (long long)N);
    int mval = 0;
    if (pok) mval = __builtin_nontemporal_load(mask + p0 + p);

    __syncthreads();

    // ---- phase 2: 128 rows, r = cb + wv; nt scalar stores (256B/wave) ----
    if (pok) {
        const long long col = p0 + p;
        // pdf^T rows 0..63
        #pragma unroll
        for (int cb = 0; cb < 64; cb += 4) {
            int c = cb + wv;
            __builtin_nontemporal_store(tile[p][c], out + (long long)c * N + col);
        }
        // te broadcast rows 64..95
        #pragma unroll
        for (int cb = 0; cb < 32; cb += 4) {
            int c = cb + wv;
            __builtin_nontemporal_store(emb[c], out + (long long)(64 + c) * N + col);
        }
        // mask-embedding rows 96..127
        #pragma unroll
        for (int cb = 0; cb < 32; cb += 4) {
            int c = cb + wv;
            __builtin_nontemporal_store(mval ? emb[64 + c] : emb[32 + c],
                                        out + (long long)(96 + c) * N + col);
        }
    }
}

extern "C" void kernel_launch(void* const* d_in, const int* in_sizes, int n_in,
                              void* d_out, int out_size, void* d_ws, size_t ws_size,
                              hipStream_t stream) {
    // 0: inputs [1,6,N]; 1: t [1]; 2: mask [N] i32; 3: pdf [N,64];
    // 4..7: ef_w1,ef_b1,ef_w2,ef_b2; 8..11: em_w1,em_b1,em_w2,em_b2
    const float* t     = (const float*)d_in[1];
    const int*   mask  = (const int*)d_in[2];
    const float* pdf   = (const float*)d_in[3];
    const float* ef_w1 = (const float*)d_in[4];
    const float* ef_b1 = (const float*)d_in[5];
    const float* ef_w2 = (const float*)d_in[6];
    const float* ef_b2 = (const float*)d_in[7];
    const float* em_w1 = (const float*)d_in[8];
    const float* em_b1 = (const float*)d_in[9];
    const float* em_w2 = (const float*)d_in[10];
    const float* em_b2 = (const float*)d_in[11];

    float* out = (float*)d_out;
    float* ws  = (float*)d_ws;
    const int N = in_sizes[2];

    embed_small_kernel<<<1, 192, 0, stream>>>(t, ef_w1, ef_b1, ef_w2, ef_b2,
                                              em_w1, em_b1, em_w2, em_b2, ws);

    const int nblocks = (N + 63) / 64;
    pvcnn_cond_kernel<<<nblocks, 256, 0, stream>>>(pdf, mask, ws, out, N);
}